// Round 2
// baseline (247.523 us; speedup 1.0000x reference)
//
#include <hip/hip_runtime.h>

#define TOPK 10
#define CLIP 0.05f
#define EPSV 1e-8f
#define ALPHA1 2.0f
#define ALPHA_OTHER 0.5f
#define TCAND 2.5f     // candidate threshold; guarded by exact fallback
#define SLOTS 128      // per-row candidate slots (lambda~60, P(overflow)~0; fallback covers)
#define MAXC 512       // old single-kernel fallback path

// sortable packed key: (monotone float key << 32) | (C - col)
// larger packed = larger value; on equal value, smaller col wins (matches lax.top_k)
__device__ __forceinline__ unsigned long long pack_vc(float v, int c, int C) {
  unsigned u = __float_as_uint(v);
  unsigned key = (u & 0x80000000u) ? ~u : (u | 0x80000000u);
  return ((unsigned long long)key << 32) | (unsigned)(C - c);
}
__device__ __forceinline__ float unpack_v(unsigned long long p) {
  unsigned key = (unsigned)(p >> 32);
  unsigned u = (key & 0x80000000u) ? (key & 0x7fffffffu) : ~key;
  return __uint_as_float(u);
}
__device__ __forceinline__ int unpack_c(unsigned long long p, int C) {
  return C - (int)(unsigned)(p & 0xffffffffu);
}

// base * w for one element. pos = (y == 1)
__device__ __forceinline__ float base_w(float xv, bool pos) {
  float p = 1.f / (1.f + __expf(-xv));          // sigmoid
  float xneg = fminf(1.f - p + CLIP, 1.f);
  float q = pos ? p : xneg;
  float b = __logf(fmaxf(q, EPSV));
  float t = 1.f - q;                             // 1 - pt
  float t2 = t * t;
  float w = pos ? t : t2 * t2;                   // gamma: pos=1, neg=4
  return b * w;
}

// process one float4: accumulate into 4 independent chains, set candidate bit
__device__ __forceinline__ void proc4(float4 X, float4 Y, float4& acc,
                                      unsigned& cmask, int slot) {
  acc.x += base_w(X.x, Y.x > 0.5f);
  acc.y += base_w(X.y, Y.y > 0.5f);
  acc.z += base_w(X.z, Y.z > 0.5f);
  acc.w += base_w(X.w, Y.w > 0.5f);
  float mx = fmaxf(fmaxf(X.x, X.y), fmaxf(X.z, X.w));
  cmask |= (mx > TCAND ? 1u : 0u) << slot;
}

// ---------------------------------------------------------------------------
// Split path: kernel A = flat streaming sum + candidate harvest (row-agnostic)
//             kernel B = per-row top-10 correction (1 wave / row)
// ---------------------------------------------------------------------------

__device__ __forceinline__ void push_cand(unsigned e, float v, int C,
                                          unsigned* cnt,
                                          unsigned long long* cand) {
  unsigned row = e / (unsigned)C;      // rare path: compiler magic-div is fine
  int col = (int)(e - row * (unsigned)C);
  unsigned i = atomicAdd(&cnt[row], 1u);
  if (i < SLOTS) cand[(size_t)row * SLOTS + i] = pack_vc(v, col, C);
}

__global__ __launch_bounds__(256) void stream_kernel(
    const float* __restrict__ x, const float* __restrict__ y,
    float* __restrict__ out, unsigned* __restrict__ cnt,
    unsigned long long* __restrict__ cand, int C, unsigned total)
{
  const int tid = threadIdx.x;
  const unsigned nth = gridDim.x * 256u;
  const unsigned gtid = blockIdx.x * 256u + tid;
  const unsigned n4 = total >> 2;
  const float4* __restrict__ x4 = (const float4*)x;
  const float4* __restrict__ y4 = (const float4*)y;

  float4 sacc = make_float4(0.f, 0.f, 0.f, 0.f);
  float ssc = 0.f;
  unsigned cmask = 0;

  // main loop: 4x unrolled, 8 loads in flight, candidates deferred to bitmask.
  // grid is sized so this is ~3 iterations with ALL blocks co-resident.
  int slotbase = 0;
  for (unsigned base = gtid; base < n4; base += 4u * nth, slotbase += 4) {
    const bool v1 = base + nth < n4;
    const bool v2 = base + 2u * nth < n4;
    const bool v3 = base + 3u * nth < n4;
    float4 xv0, xv1, xv2, xv3, yv0, yv1, yv2, yv3;
    xv0 = x4[base];                  yv0 = y4[base];
    if (v1) { xv1 = x4[base + nth];      yv1 = y4[base + nth]; }
    if (v2) { xv2 = x4[base + 2u * nth]; yv2 = y4[base + 2u * nth]; }
    if (v3) { xv3 = x4[base + 3u * nth]; yv3 = y4[base + 3u * nth]; }
    if (slotbase <= 28) {            // bitmask path (always taken at this size)
      proc4(xv0, yv0, sacc, cmask, slotbase + 0);
      if (v1) proc4(xv1, yv1, sacc, cmask, slotbase + 1);
      if (v2) proc4(xv2, yv2, sacc, cmask, slotbase + 2);
      if (v3) proc4(xv3, yv3, sacc, cmask, slotbase + 3);
    } else {                         // generic overflow: push candidates inline
      float4 X[4] = {xv0, xv1, xv2, xv3};
      float4 Y[4] = {yv0, yv1, yv2, yv3};
      bool vv[4] = {true, v1, v2, v3};
#pragma unroll
      for (int k = 0; k < 4; k++) {
        if (!vv[k]) break;
        sacc.x += base_w(X[k].x, Y[k].x > 0.5f);
        sacc.y += base_w(X[k].y, Y[k].y > 0.5f);
        sacc.z += base_w(X[k].z, Y[k].z > 0.5f);
        sacc.w += base_w(X[k].w, Y[k].w > 0.5f);
        unsigned e = (base + (unsigned)k * nth) * 4u;
        if (X[k].x > TCAND) push_cand(e + 0, X[k].x, C, cnt, cand);
        if (X[k].y > TCAND) push_cand(e + 1, X[k].y, C, cnt, cand);
        if (X[k].z > TCAND) push_cand(e + 2, X[k].z, C, cnt, cand);
        if (X[k].w > TCAND) push_cand(e + 3, X[k].w, C, cnt, cand);
      }
    }
  }

  // scalar tail (empty when total % 4 == 0)
  for (unsigned i = (n4 << 2) + gtid; i < total; i += nth) {
    float xv = x[i];
    ssc += base_w(xv, y[i] > 0.5f);
    if (xv > TCAND) push_cand(i, xv, C, cnt, cand);
  }

  // materialize candidates from the bitmask (cache-warm reloads, off hot path)
  while (cmask) {
    int b = __ffs(cmask) - 1;
    cmask &= cmask - 1;
    unsigned i4 = gtid + (unsigned)b * nth;
    float4 X = x4[i4];
    unsigned e = i4 * 4u;
    if (X.x > TCAND) push_cand(e + 0, X.x, C, cnt, cand);
    if (X.y > TCAND) push_cand(e + 1, X.y, C, cnt, cand);
    if (X.z > TCAND) push_cand(e + 2, X.z, C, cnt, cand);
    if (X.w > TCAND) push_cand(e + 3, X.w, C, cnt, cand);
  }

  // block reduce -> one atomic per block
  float sum = ssc + sacc.x + sacc.y + sacc.z + sacc.w;
#pragma unroll
  for (int off = 32; off > 0; off >>= 1) sum += __shfl_xor(sum, off, 64);
  __shared__ float s_sum[4];
  const int lane = tid & 63, wave = tid >> 6;
  if (lane == 0) s_sum[wave] = sum;
  __syncthreads();
  if (tid == 0) atomicAdd(out, -(s_sum[0] + s_sum[1] + s_sum[2] + s_sum[3]));
}

__global__ __launch_bounds__(64) void topk_kernel(
    const float* __restrict__ x, const float* __restrict__ y,
    const int* __restrict__ compost, const int* __restrict__ recycle,
    const int* __restrict__ donate, const int* __restrict__ wl_map,
    float* __restrict__ out, const unsigned* __restrict__ cnt,
    const unsigned long long* __restrict__ cand,
    int C, int n1, int n2, int n3)
{
  const int row = blockIdx.x;
  const int lane = threadIdx.x;
  const float* __restrict__ xr = x + (size_t)row * (size_t)C;
  const float* __restrict__ yr = y + (size_t)row * (size_t)C;

  // whitelist group flags via ballot (y row is L2/L3-warm from kernel A)
  const int ntot = n1 + n2 + n3;
  bool f1 = false, f2 = false, f3 = false;
  for (int i = lane; i < ntot; i += 64) {
    int colI;
    if (i < n1)           { colI = compost[i];           if (yr[colI] > 0.5f) f1 = true; }
    else if (i < n1 + n2) { colI = recycle[i - n1];      if (yr[colI] > 0.5f) f2 = true; }
    else                  { colI = donate[i - n1 - n2];  if (yr[colI] > 0.5f) f3 = true; }
  }
  const bool h1 = __ballot(f1) != 0ULL;
  const bool h2 = __ballot(f2) != 0ULL;
  const bool h3 = __ballot(f3) != 0ULL;
  const bool gt4 = !(h1 || h2 || h3);

  // exact top-10: candidate list if trustworthy, else full-row rescan
  const unsigned c = cnt[row];
  unsigned long long ls[TOPK];
#pragma unroll
  for (int s = 0; s < TOPK; s++) ls[s] = 0ULL;

#define INSERT(P)                                                          \
  do {                                                                     \
    unsigned long long _p = (P);                                           \
    if (_p > ls[TOPK - 1]) {                                               \
      _Pragma("unroll")                                                    \
      for (int _s = 0; _s < TOPK; _s++) {                                  \
        bool _g = _p > ls[_s];                                             \
        unsigned long long _t = _g ? ls[_s] : _p;                          \
        ls[_s] = _g ? _p : ls[_s];                                         \
        _p = _t;                                                           \
      }                                                                    \
    }                                                                      \
  } while (0)

  if (c >= TOPK && c <= SLOTS) {
    const unsigned long long* cr = cand + (size_t)row * SLOTS;
    for (unsigned i = lane; i < c; i += 64) INSERT(cr[i]);
  } else {
    for (int col = lane; col < C; col += 64) INSERT(pack_vc(xr[col], col, C));
  }
#undef INSERT

  // 10 rounds of 64-lane packed max; rank r lands on lane r (packed vals unique)
  unsigned long long myTop = 0ULL;
  for (int r = 0; r < TOPK; r++) {
    unsigned long long mine = ls[0];
    unsigned long long best = mine;
#pragma unroll
    for (int off = 32; off > 0; off >>= 1) {
      unsigned long long o = __shfl_xor(best, off, 64);
      best = (o > best) ? o : best;
    }
    if (lane == r) myTop = best;
    if (mine == best) {
#pragma unroll
      for (int s = 0; s < TOPK - 1; s++) ls[s] = ls[s + 1];
      ls[TOPK - 1] = 0ULL;
    }
  }

  // parallel rank-sequential multiplier: the scan's `found` carry is a ballot prefix
  const bool valid = (lane < TOPK) && (myTop != 0ULL);
  int col = 0; float val = 0.f; int wl = 0;
  if (valid) {
    col = unpack_c(myTop, C);
    val = unpack_v(myTop);
    wl = wl_map[col];
  }
  const bool in_map = valid && (wl > 0);
  const bool in_gt = in_map && ((wl == 1 && h1) || (wl == 2 && h2) ||
                                (wl == 3 && h3) || (wl == 4 && gt4));
  const unsigned long long mm = __ballot(in_map && in_gt);
  const bool foundbefore = (mm & ((1ULL << lane) - 1ULL)) != 0ULL;
  float f = 1.f;
  if (in_map && gt4) f *= ALPHA_OTHER;
  if (in_map && !in_gt && !foundbefore) f *= ALPHA1;
  const float extra = (mm != 0ULL) ? 1.f : ALPHA1;

  float corr = 0.f;
  if (valid) {
    float mult = f * extra;
    if (mult != 1.f) corr = (mult - 1.f) * base_w(val, yr[col] > 0.5f);
  }
#pragma unroll
  for (int off = 32; off > 0; off >>= 1) corr += __shfl_xor(corr, off, 64);
  if (lane == 0 && corr != 0.f) atomicAdd(out, -corr);
}

// ---------------------------------------------------------------------------
// Fallback: previous verified single-kernel path (used if workspace too small)
// ---------------------------------------------------------------------------

__global__ __launch_bounds__(256) void asl_kernel(
    const float* __restrict__ x, const float* __restrict__ y,
    const int* __restrict__ compost, const int* __restrict__ recycle,
    const int* __restrict__ donate, const int* __restrict__ wl_map,
    float* __restrict__ out, int C, int n1, int n2, int n3)
{
  const int row = blockIdx.x;
  const float* xr = x + (size_t)row * (size_t)C;
  const float* yr = y + (size_t)row * (size_t)C;
  const int tid = threadIdx.x;
  const int lane = tid & 63;
  const int wave = tid >> 6;

  __shared__ int s_has[3];
  __shared__ unsigned s_cnt;
  __shared__ unsigned long long s_cand[MAXC];
  __shared__ float s_sum[4];
  __shared__ unsigned long long s_top[TOPK];

  if (tid < 3) s_has[tid] = 0;
  if (tid == 0) s_cnt = 0;
  __syncthreads();

  const int ntot = n1 + n2 + n3;
  float gflag = 0.f; int gwhich = -1;
  if (tid < ntot) {
    int colI;
    if (tid < n1)           { gwhich = 0; colI = compost[tid]; }
    else if (tid < n1 + n2) { gwhich = 1; colI = recycle[tid - n1]; }
    else                    { gwhich = 2; colI = donate[tid - n1 - n2]; }
    gflag = yr[colI];
  }

  float ssc = 0.f;

#define PUSH(V, CCOL)                                                     \
  do {                                                                    \
    unsigned _i = atomicAdd(&s_cnt, 1u);                                  \
    if (_i < MAXC) s_cand[_i] = pack_vc((V), (CCOL), C);                  \
  } while (0)
#define PROC_DIRECT(XV, YV, COL)                                          \
  do {                                                                    \
    float _xv = (XV);                                                     \
    ssc += base_w(_xv, (YV) > 0.5f);                                      \
    if (_xv > TCAND) PUSH(_xv, (COL));                                    \
  } while (0)

  int lead = (int)((4u - ((unsigned)((size_t)row * (size_t)C) & 3u)) & 3u);
  if (lead > C) lead = C;
  for (int col = tid; col < lead; col += 256) PROC_DIRECT(xr[col], yr[col], col);

  const int nvec = (C - lead) >> 2;
  const float4* __restrict__ x4 = (const float4*)(xr + lead);
  const float4* __restrict__ y4 = (const float4*)(yr + lead);

  float4 sacc = make_float4(0.f, 0.f, 0.f, 0.f);
  unsigned cmask = 0;

  int slotbase = 0;
  for (int base = tid; base < nvec; base += 1024, slotbase += 4) {
    const bool v1 = base + 256 < nvec;
    const bool v2 = base + 512 < nvec;
    const bool v3 = base + 768 < nvec;
    float4 xv0, xv1, xv2, xv3, yv0, yv1, yv2, yv3;
    xv0 = x4[base];                 yv0 = y4[base];
    if (v1) { xv1 = x4[base + 256]; yv1 = y4[base + 256]; }
    if (v2) { xv2 = x4[base + 512]; yv2 = y4[base + 512]; }
    if (v3) { xv3 = x4[base + 768]; yv3 = y4[base + 768]; }
    proc4(xv0, yv0, sacc, cmask, slotbase + 0);
    if (v1) proc4(xv1, yv1, sacc, cmask, slotbase + 1);
    if (v2) proc4(xv2, yv2, sacc, cmask, slotbase + 2);
    if (v3) proc4(xv3, yv3, sacc, cmask, slotbase + 3);
  }

  for (int col = lead + nvec * 4 + tid; col < C; col += 256)
    PROC_DIRECT(xr[col], yr[col], col);

  if (gwhich >= 0 && gflag > 0.5f) s_has[gwhich] = 1;
  for (int i = 256 + tid; i < ntot; i += 256) {
    int which, colI;
    if (i < n1)           { which = 0; colI = compost[i]; }
    else if (i < n1 + n2) { which = 1; colI = recycle[i - n1]; }
    else                  { which = 2; colI = donate[i - n1 - n2]; }
    if (yr[colI] > 0.5f) s_has[which] = 1;
  }

  while (cmask) {
    int b = __ffs(cmask) - 1;
    cmask &= cmask - 1;
    int o = b >> 2, j = b & 3;
    int i = tid + o * 1024 + j * 256;
    float4 X = x4[i];
    int cb = lead + i * 4;
    if (X.x > TCAND) PUSH(X.x, cb + 0);
    if (X.y > TCAND) PUSH(X.y, cb + 1);
    if (X.z > TCAND) PUSH(X.z, cb + 2);
    if (X.w > TCAND) PUSH(X.w, cb + 3);
  }
#undef PROC_DIRECT
#undef PUSH

  float sum = ssc + sacc.x + sacc.y + sacc.z + sacc.w;
#pragma unroll
  for (int off = 32; off > 0; off >>= 1) sum += __shfl_xor(sum, off, 64);
  if (lane == 0) s_sum[wave] = sum;
  __syncthreads();

  if (wave == 0) {
    const unsigned cnt = s_cnt;
    unsigned long long ls[TOPK];
#pragma unroll
    for (int s = 0; s < TOPK; s++) ls[s] = 0ULL;

#define INSERT(P)                                                          \
    do {                                                                   \
      unsigned long long _p = (P);                                         \
      if (_p > ls[TOPK - 1]) {                                             \
        _Pragma("unroll")                                                  \
        for (int _s = 0; _s < TOPK; _s++) {                                \
          bool _g = _p > ls[_s];                                           \
          unsigned long long _t = _g ? ls[_s] : _p;                        \
          ls[_s] = _g ? _p : ls[_s];                                       \
          _p = _t;                                                         \
        }                                                                  \
      }                                                                    \
    } while (0)

    if (cnt >= TOPK && cnt <= MAXC) {
      for (unsigned i = lane; i < cnt; i += 64) INSERT(s_cand[i]);
    } else {
      for (int col = lane; col < C; col += 64) INSERT(pack_vc(xr[col], col, C));
    }
#undef INSERT

    for (int r = 0; r < TOPK; r++) {
      unsigned long long mine = ls[0];
      unsigned long long best = mine;
#pragma unroll
      for (int off = 32; off > 0; off >>= 1) {
        unsigned long long o = __shfl_xor(best, off, 64);
        best = (o > best) ? o : best;
      }
      if (lane == 0) s_top[r] = best;
      if (mine == best) {
#pragma unroll
        for (int s = 0; s < TOPK - 1; s++) ls[s] = ls[s + 1];
        ls[TOPK - 1] = 0ULL;
      }
    }
  }
  __syncthreads();

  if (tid == 0) {
    float total = s_sum[0] + s_sum[1] + s_sum[2] + s_sum[3];
    const bool h1 = s_has[0] != 0, h2 = s_has[1] != 0, h3 = s_has[2] != 0;
    const bool gt4 = !(h1 || h2 || h3);

    bool found = false;
    float fr[TOPK];
#pragma unroll
    for (int r = 0; r < TOPK; r++) {
      int col = unpack_c(s_top[r], C);
      int wl = wl_map[col];
      bool in_map = wl > 0;
      bool in_gt = (wl == 1 && h1) || (wl == 2 && h2) ||
                   (wl == 3 && h3) || (wl == 4 && gt4);
      float f = 1.f;
      if (in_map && gt4) f *= ALPHA_OTHER;
      if (in_map && !in_gt && !found) f *= ALPHA1;
      fr[r] = f;
      found = found || (in_map && in_gt);
    }
    const float extra = found ? 1.f : ALPHA1;
#pragma unroll
    for (int r = 0; r < TOPK; r++) {
      float mult = fr[r] * extra;
      if (mult != 1.f) {
        int col = unpack_c(s_top[r], C);
        float xv = unpack_v(s_top[r]);
        float bwv = base_w(xv, yr[col] > 0.5f);
        total += (mult - 1.f) * bwv;
      }
    }
    atomicAdd(out, -total);
  }
}

extern "C" void kernel_launch(void* const* d_in, const int* in_sizes, int n_in,
                              void* d_out, int out_size, void* d_ws, size_t ws_size,
                              hipStream_t stream) {
  const float* x       = (const float*)d_in[0];
  const float* y       = (const float*)d_in[1];
  const int*   compost = (const int*)d_in[2];
  const int*   recycle = (const int*)d_in[3];
  const int*   donate  = (const int*)d_in[4];
  const int*   wl_map  = (const int*)d_in[5];
  float* out = (float*)d_out;

  const int C  = in_sizes[5];
  const int B  = in_sizes[0] / C;
  const int n1 = in_sizes[2], n2 = in_sizes[3], n3 = in_sizes[4];

  hipMemsetAsync(out, 0, sizeof(float), stream);

  const size_t cntBytes = (size_t)B * 4;
  const size_t candOff  = (cntBytes + 15) & ~(size_t)15;
  const size_t need     = candOff + (size_t)B * SLOTS * 8;

  if (d_ws != nullptr && ws_size >= need) {
    unsigned* cnt = (unsigned*)d_ws;
    unsigned long long* cand = (unsigned long long*)((char*)d_ws + candOff);
    hipMemsetAsync(cnt, 0, cntBytes, stream);

    const size_t totalS = (size_t)B * (size_t)C;
    const unsigned total = (unsigned)totalS;
    size_t n4s = totalS / 4;
    int nblk = (int)((n4s + 255) / 256);
    if (nblk > 2048) nblk = 2048;   // 2048 x 256 = exact resident capacity
    if (nblk < 1) nblk = 1;

    stream_kernel<<<nblk, 256, 0, stream>>>(x, y, out, cnt, cand, C, total);
    topk_kernel<<<B, 64, 0, stream>>>(x, y, compost, recycle, donate, wl_map,
                                      out, cnt, cand, C, n1, n2, n3);
  } else {
    asl_kernel<<<B, 256, 0, stream>>>(x, y, compost, recycle, donate, wl_map,
                                      out, C, n1, n2, n3);
  }
}

// Round 3
// 246.892 us; speedup vs baseline: 1.0026x; 1.0026x over previous
//
#include <hip/hip_runtime.h>

#define TOPK 10
#define CLIP 0.05f
#define EPSV 1e-8f
#define ALPHA1 2.0f
#define ALPHA_OTHER 0.5f
#define TCAND 2.5f     // candidate threshold; guarded by exact fallback
#define SLOTS 128      // per-row candidate slots (lambda~60, P(overflow)~0; fallback covers)
#define MAXC 512       // old single-kernel fallback path

// sortable packed key: (monotone float key << 32) | (C - col)
// larger packed = larger value; on equal value, smaller col wins (matches lax.top_k)
__device__ __forceinline__ unsigned long long pack_vc(float v, int c, int C) {
  unsigned u = __float_as_uint(v);
  unsigned key = (u & 0x80000000u) ? ~u : (u | 0x80000000u);
  return ((unsigned long long)key << 32) | (unsigned)(C - c);
}
__device__ __forceinline__ float unpack_v(unsigned long long p) {
  unsigned key = (unsigned)(p >> 32);
  unsigned u = (key & 0x80000000u) ? (key & 0x7fffffffu) : ~key;
  return __uint_as_float(u);
}
__device__ __forceinline__ int unpack_c(unsigned long long p, int C) {
  return C - (int)(unsigned)(p & 0xffffffffu);
}

// base * w for one element. pos = (y == 1)  -- numerics identical to verified version
__device__ __forceinline__ float base_w(float xv, bool pos) {
  float p = 1.f / (1.f + __expf(-xv));          // sigmoid
  float xneg = fminf(1.f - p + CLIP, 1.f);
  float q = pos ? p : xneg;
  float b = __logf(fmaxf(q, EPSV));
  float t = 1.f - q;                             // 1 - pt
  float t2 = t * t;
  float w = pos ? t : t2 * t2;                   // gamma: pos=1, neg=4
  return b * w;
}

// process one float4: accumulate into 4 independent chains, set candidate bit
__device__ __forceinline__ void proc4(float4 X, float4 Y, float4& acc,
                                      unsigned& cmask, int slot) {
  acc.x += base_w(X.x, Y.x > 0.5f);
  acc.y += base_w(X.y, Y.y > 0.5f);
  acc.z += base_w(X.z, Y.z > 0.5f);
  acc.w += base_w(X.w, Y.w > 0.5f);
  float mx = fmaxf(fmaxf(X.x, X.y), fmaxf(X.z, X.w));
  cmask |= (mx > TCAND ? 1u : 0u) << slot;
}

__device__ __forceinline__ void push_cand(unsigned e, float v, int C,
                                          unsigned* cnt,
                                          unsigned long long* cand) {
  unsigned row = e / (unsigned)C;      // rare path: compiler magic-div is fine
  int col = (int)(e - row * (unsigned)C);
  unsigned i = atomicAdd(&cnt[row], 1u);
  if (i < SLOTS) cand[(size_t)row * SLOTS + i] = pack_vc(v, col, C);
}

// slot-overflow path: accumulate + push candidates inline (generic shapes only)
__device__ __forceinline__ void proc4_push(float4 X, float4 Y, float4& acc,
                                           unsigned e0, int C, unsigned* cnt,
                                           unsigned long long* cand) {
  acc.x += base_w(X.x, Y.x > 0.5f);
  acc.y += base_w(X.y, Y.y > 0.5f);
  acc.z += base_w(X.z, Y.z > 0.5f);
  acc.w += base_w(X.w, Y.w > 0.5f);
  if (X.x > TCAND) push_cand(e0 + 0, X.x, C, cnt, cand);
  if (X.y > TCAND) push_cand(e0 + 1, X.y, C, cnt, cand);
  if (X.z > TCAND) push_cand(e0 + 2, X.z, C, cnt, cand);
  if (X.w > TCAND) push_cand(e0 + 3, X.w, C, cnt, cand);
}

// ---------------------------------------------------------------------------
// Kernel A: flat streaming sum + candidate harvest, software-pipelined.
// Ping-pong register double-buffer: stage s+1's loads issue BEFORE stage s's
// compute, so VMEM latency hides under ~600 cyc of VALU per stage per wave.
// Statically unrolled A/B phases: no register moves, no runtime-indexed arrays.
// ---------------------------------------------------------------------------

__global__ __launch_bounds__(256) void stream_kernel(
    const float* __restrict__ x, const float* __restrict__ y,
    float* __restrict__ out, unsigned* __restrict__ cnt,
    unsigned long long* __restrict__ cand, int C, unsigned total)
{
  const int tid = threadIdx.x;
  const unsigned nth = gridDim.x * 256u;
  const unsigned gtid = blockIdx.x * 256u + tid;
  const unsigned n4 = total >> 2;
  const float4* __restrict__ x4 = (const float4*)x;
  const float4* __restrict__ y4 = (const float4*)y;

  float4 sacc = make_float4(0.f, 0.f, 0.f, 0.f);
  float ssc = 0.f;
  unsigned cmask = 0;

  // bit b of cmask -> stage (b>>1) over stride `step`, half (b&1) over `nth`
#define DO_PAIR(XV, YV, IDX4, SLOT)                                        \
  do {                                                                     \
    if ((SLOT) < 30) proc4((XV), (YV), sacc, cmask, (SLOT));               \
    else proc4_push((XV), (YV), sacc, (IDX4) * 4u, C, cnt, cand);          \
  } while (0)

  const unsigned step = 2u * nth;
  unsigned sA = gtid;
  bool a0v = sA < n4;
  bool a1v = (sA + nth) < n4;
  float4 xa0, ya0, xa1, ya1, xb0, yb0, xb1, yb1;
  if (a0v) { xa0 = x4[sA];       ya0 = y4[sA]; }
  if (a1v) { xa1 = x4[sA + nth]; ya1 = y4[sA + nth]; }
  int slot = 0;

  while (a0v) {
    // prefetch stage B
    const unsigned sB = sA + step;
    const bool b0v = sB < n4;
    const bool b1v = (sB + nth) < n4;
    if (b0v) { xb0 = x4[sB];       yb0 = y4[sB]; }
    if (b1v) { xb1 = x4[sB + nth]; yb1 = y4[sB + nth]; }

    // compute stage A (loads for B already in flight)
    DO_PAIR(xa0, ya0, sA, slot);
    if (a1v) DO_PAIR(xa1, ya1, sA + nth, slot + 1);
    slot += 2;
    if (!b0v) break;

    // prefetch stage C (into the A registers)
    const unsigned sC = sB + step;
    const bool c0v = sC < n4;
    const bool c1v = (sC + nth) < n4;
    if (c0v) { xa0 = x4[sC];       ya0 = y4[sC]; }
    if (c1v) { xa1 = x4[sC + nth]; ya1 = y4[sC + nth]; }

    // compute stage B
    DO_PAIR(xb0, yb0, sB, slot);
    if (b1v) DO_PAIR(xb1, yb1, sB + nth, slot + 1);
    slot += 2;

    sA = sC; a0v = c0v; a1v = c1v;
  }
#undef DO_PAIR

  // scalar tail (empty when total % 4 == 0)
  for (unsigned i = (n4 << 2) + gtid; i < total; i += nth) {
    float xv = x[i];
    ssc += base_w(xv, y[i] > 0.5f);
    if (xv > TCAND) push_cand(i, xv, C, cnt, cand);
  }

  // materialize candidates from the bitmask (cache-warm reloads, off hot path)
  while (cmask) {
    int b = __ffs(cmask) - 1;
    cmask &= cmask - 1;
    unsigned i4 = gtid + (unsigned)(b >> 1) * step + (unsigned)(b & 1) * nth;
    float4 X = x4[i4];
    unsigned e = i4 * 4u;
    if (X.x > TCAND) push_cand(e + 0, X.x, C, cnt, cand);
    if (X.y > TCAND) push_cand(e + 1, X.y, C, cnt, cand);
    if (X.z > TCAND) push_cand(e + 2, X.z, C, cnt, cand);
    if (X.w > TCAND) push_cand(e + 3, X.w, C, cnt, cand);
  }

  // block reduce -> one atomic per block
  float sum = ssc + sacc.x + sacc.y + sacc.z + sacc.w;
#pragma unroll
  for (int off = 32; off > 0; off >>= 1) sum += __shfl_xor(sum, off, 64);
  __shared__ float s_sum[4];
  const int lane = tid & 63, wave = tid >> 6;
  if (lane == 0) s_sum[wave] = sum;
  __syncthreads();
  if (tid == 0) atomicAdd(out, -(s_sum[0] + s_sum[1] + s_sum[2] + s_sum[3]));
}

__global__ __launch_bounds__(64) void topk_kernel(
    const float* __restrict__ x, const float* __restrict__ y,
    const int* __restrict__ compost, const int* __restrict__ recycle,
    const int* __restrict__ donate, const int* __restrict__ wl_map,
    float* __restrict__ out, const unsigned* __restrict__ cnt,
    const unsigned long long* __restrict__ cand,
    int C, int n1, int n2, int n3)
{
  const int row = blockIdx.x;
  const int lane = threadIdx.x;
  const float* __restrict__ xr = x + (size_t)row * (size_t)C;
  const float* __restrict__ yr = y + (size_t)row * (size_t)C;

  // whitelist group flags via ballot (y row is L2/L3-warm from kernel A)
  const int ntot = n1 + n2 + n3;
  bool f1 = false, f2 = false, f3 = false;
  for (int i = lane; i < ntot; i += 64) {
    int colI;
    if (i < n1)           { colI = compost[i];           if (yr[colI] > 0.5f) f1 = true; }
    else if (i < n1 + n2) { colI = recycle[i - n1];      if (yr[colI] > 0.5f) f2 = true; }
    else                  { colI = donate[i - n1 - n2];  if (yr[colI] > 0.5f) f3 = true; }
  }
  const bool h1 = __ballot(f1) != 0ULL;
  const bool h2 = __ballot(f2) != 0ULL;
  const bool h3 = __ballot(f3) != 0ULL;
  const bool gt4 = !(h1 || h2 || h3);

  // exact top-10: candidate list if trustworthy, else full-row rescan
  const unsigned c = cnt[row];
  unsigned long long ls[TOPK];
#pragma unroll
  for (int s = 0; s < TOPK; s++) ls[s] = 0ULL;

#define INSERT(P)                                                          \
  do {                                                                     \
    unsigned long long _p = (P);                                           \
    if (_p > ls[TOPK - 1]) {                                               \
      _Pragma("unroll")                                                    \
      for (int _s = 0; _s < TOPK; _s++) {                                  \
        bool _g = _p > ls[_s];                                             \
        unsigned long long _t = _g ? ls[_s] : _p;                          \
        ls[_s] = _g ? _p : ls[_s];                                         \
        _p = _t;                                                           \
      }                                                                    \
    }                                                                      \
  } while (0)

  if (c >= TOPK && c <= SLOTS) {
    const unsigned long long* cr = cand + (size_t)row * SLOTS;
    for (unsigned i = lane; i < c; i += 64) INSERT(cr[i]);
  } else {
    for (int col = lane; col < C; col += 64) INSERT(pack_vc(xr[col], col, C));
  }
#undef INSERT

  // 10 rounds of 64-lane packed max; rank r lands on lane r (packed vals unique)
  unsigned long long myTop = 0ULL;
  for (int r = 0; r < TOPK; r++) {
    unsigned long long mine = ls[0];
    unsigned long long best = mine;
#pragma unroll
    for (int off = 32; off > 0; off >>= 1) {
      unsigned long long o = __shfl_xor(best, off, 64);
      best = (o > best) ? o : best;
    }
    if (lane == r) myTop = best;
    if (mine == best) {
#pragma unroll
      for (int s = 0; s < TOPK - 1; s++) ls[s] = ls[s + 1];
      ls[TOPK - 1] = 0ULL;
    }
  }

  // parallel rank-sequential multiplier: the scan's `found` carry is a ballot prefix
  const bool valid = (lane < TOPK) && (myTop != 0ULL);
  int col = 0; float val = 0.f; int wl = 0;
  if (valid) {
    col = unpack_c(myTop, C);
    val = unpack_v(myTop);
    wl = wl_map[col];
  }
  const bool in_map = valid && (wl > 0);
  const bool in_gt = in_map && ((wl == 1 && h1) || (wl == 2 && h2) ||
                                (wl == 3 && h3) || (wl == 4 && gt4));
  const unsigned long long mm = __ballot(in_map && in_gt);
  const bool foundbefore = (mm & ((1ULL << lane) - 1ULL)) != 0ULL;
  float f = 1.f;
  if (in_map && gt4) f *= ALPHA_OTHER;
  if (in_map && !in_gt && !foundbefore) f *= ALPHA1;
  const float extra = (mm != 0ULL) ? 1.f : ALPHA1;

  float corr = 0.f;
  if (valid) {
    float mult = f * extra;
    if (mult != 1.f) corr = (mult - 1.f) * base_w(val, yr[col] > 0.5f);
  }
#pragma unroll
  for (int off = 32; off > 0; off >>= 1) corr += __shfl_xor(corr, off, 64);
  if (lane == 0 && corr != 0.f) atomicAdd(out, -corr);
}

// ---------------------------------------------------------------------------
// Fallback: previous verified single-kernel path (used if workspace too small)
// ---------------------------------------------------------------------------

__global__ __launch_bounds__(256) void asl_kernel(
    const float* __restrict__ x, const float* __restrict__ y,
    const int* __restrict__ compost, const int* __restrict__ recycle,
    const int* __restrict__ donate, const int* __restrict__ wl_map,
    float* __restrict__ out, int C, int n1, int n2, int n3)
{
  const int row = blockIdx.x;
  const float* xr = x + (size_t)row * (size_t)C;
  const float* yr = y + (size_t)row * (size_t)C;
  const int tid = threadIdx.x;
  const int lane = tid & 63;
  const int wave = tid >> 6;

  __shared__ int s_has[3];
  __shared__ unsigned s_cnt;
  __shared__ unsigned long long s_cand[MAXC];
  __shared__ float s_sum[4];
  __shared__ unsigned long long s_top[TOPK];

  if (tid < 3) s_has[tid] = 0;
  if (tid == 0) s_cnt = 0;
  __syncthreads();

  const int ntot = n1 + n2 + n3;
  float gflag = 0.f; int gwhich = -1;
  if (tid < ntot) {
    int colI;
    if (tid < n1)           { gwhich = 0; colI = compost[tid]; }
    else if (tid < n1 + n2) { gwhich = 1; colI = recycle[tid - n1]; }
    else                    { gwhich = 2; colI = donate[tid - n1 - n2]; }
    gflag = yr[colI];
  }

  float ssc = 0.f;

#define PUSH(V, CCOL)                                                     \
  do {                                                                    \
    unsigned _i = atomicAdd(&s_cnt, 1u);                                  \
    if (_i < MAXC) s_cand[_i] = pack_vc((V), (CCOL), C);                  \
  } while (0)
#define PROC_DIRECT(XV, YV, COL)                                          \
  do {                                                                    \
    float _xv = (XV);                                                     \
    ssc += base_w(_xv, (YV) > 0.5f);                                      \
    if (_xv > TCAND) PUSH(_xv, (COL));                                    \
  } while (0)

  int lead = (int)((4u - ((unsigned)((size_t)row * (size_t)C) & 3u)) & 3u);
  if (lead > C) lead = C;
  for (int col = tid; col < lead; col += 256) PROC_DIRECT(xr[col], yr[col], col);

  const int nvec = (C - lead) >> 2;
  const float4* __restrict__ x4 = (const float4*)(xr + lead);
  const float4* __restrict__ y4 = (const float4*)(yr + lead);

  float4 sacc = make_float4(0.f, 0.f, 0.f, 0.f);
  unsigned cmask = 0;

  int slotbase = 0;
  for (int base = tid; base < nvec; base += 1024, slotbase += 4) {
    const bool v1 = base + 256 < nvec;
    const bool v2 = base + 512 < nvec;
    const bool v3 = base + 768 < nvec;
    float4 xv0, xv1, xv2, xv3, yv0, yv1, yv2, yv3;
    xv0 = x4[base];                 yv0 = y4[base];
    if (v1) { xv1 = x4[base + 256]; yv1 = y4[base + 256]; }
    if (v2) { xv2 = x4[base + 512]; yv2 = y4[base + 512]; }
    if (v3) { xv3 = x4[base + 768]; yv3 = y4[base + 768]; }
    proc4(xv0, yv0, sacc, cmask, slotbase + 0);
    if (v1) proc4(xv1, yv1, sacc, cmask, slotbase + 1);
    if (v2) proc4(xv2, yv2, sacc, cmask, slotbase + 2);
    if (v3) proc4(xv3, yv3, sacc, cmask, slotbase + 3);
  }

  for (int col = lead + nvec * 4 + tid; col < C; col += 256)
    PROC_DIRECT(xr[col], yr[col], col);

  if (gwhich >= 0 && gflag > 0.5f) s_has[gwhich] = 1;
  for (int i = 256 + tid; i < ntot; i += 256) {
    int which, colI;
    if (i < n1)           { which = 0; colI = compost[i]; }
    else if (i < n1 + n2) { which = 1; colI = recycle[i - n1]; }
    else                  { which = 2; colI = donate[i - n1 - n2]; }
    if (yr[colI] > 0.5f) s_has[which] = 1;
  }

  while (cmask) {
    int b = __ffs(cmask) - 1;
    cmask &= cmask - 1;
    int o = b >> 2, j = b & 3;
    int i = tid + o * 1024 + j * 256;
    float4 X = x4[i];
    int cb = lead + i * 4;
    if (X.x > TCAND) PUSH(X.x, cb + 0);
    if (X.y > TCAND) PUSH(X.y, cb + 1);
    if (X.z > TCAND) PUSH(X.z, cb + 2);
    if (X.w > TCAND) PUSH(X.w, cb + 3);
  }
#undef PROC_DIRECT
#undef PUSH

  float sum = ssc + sacc.x + sacc.y + sacc.z + sacc.w;
#pragma unroll
  for (int off = 32; off > 0; off >>= 1) sum += __shfl_xor(sum, off, 64);
  if (lane == 0) s_sum[wave] = sum;
  __syncthreads();

  if (wave == 0) {
    const unsigned cnt = s_cnt;
    unsigned long long ls[TOPK];
#pragma unroll
    for (int s = 0; s < TOPK; s++) ls[s] = 0ULL;

#define INSERT(P)                                                          \
    do {                                                                   \
      unsigned long long _p = (P);                                         \
      if (_p > ls[TOPK - 1]) {                                             \
        _Pragma("unroll")                                                  \
        for (int _s = 0; _s < TOPK; _s++) {                                \
          bool _g = _p > ls[_s];                                           \
          unsigned long long _t = _g ? ls[_s] : _p;                        \
          ls[_s] = _g ? _p : ls[_s];                                       \
          _p = _t;                                                         \
        }                                                                  \
      }                                                                    \
    } while (0)

    if (cnt >= TOPK && cnt <= MAXC) {
      for (unsigned i = lane; i < cnt; i += 64) INSERT(s_cand[i]);
    } else {
      for (int col = lane; col < C; col += 64) INSERT(pack_vc(xr[col], col, C));
    }
#undef INSERT

    for (int r = 0; r < TOPK; r++) {
      unsigned long long mine = ls[0];
      unsigned long long best = mine;
#pragma unroll
      for (int off = 32; off > 0; off >>= 1) {
        unsigned long long o = __shfl_xor(best, off, 64);
        best = (o > best) ? o : best;
      }
      if (lane == 0) s_top[r] = best;
      if (mine == best) {
#pragma unroll
        for (int s = 0; s < TOPK - 1; s++) ls[s] = ls[s + 1];
        ls[TOPK - 1] = 0ULL;
      }
    }
  }
  __syncthreads();

  if (tid == 0) {
    float total = s_sum[0] + s_sum[1] + s_sum[2] + s_sum[3];
    const bool h1 = s_has[0] != 0, h2 = s_has[1] != 0, h3 = s_has[2] != 0;
    const bool gt4 = !(h1 || h2 || h3);

    bool found = false;
    float fr[TOPK];
#pragma unroll
    for (int r = 0; r < TOPK; r++) {
      int col = unpack_c(s_top[r], C);
      int wl = wl_map[col];
      bool in_map = wl > 0;
      bool in_gt = (wl == 1 && h1) || (wl == 2 && h2) ||
                   (wl == 3 && h3) || (wl == 4 && gt4);
      float f = 1.f;
      if (in_map && gt4) f *= ALPHA_OTHER;
      if (in_map && !in_gt && !found) f *= ALPHA1;
      fr[r] = f;
      found = found || (in_map && in_gt);
    }
    const float extra = found ? 1.f : ALPHA1;
#pragma unroll
    for (int r = 0; r < TOPK; r++) {
      float mult = fr[r] * extra;
      if (mult != 1.f) {
        int col = unpack_c(s_top[r], C);
        float xv = unpack_v(s_top[r]);
        float bwv = base_w(xv, yr[col] > 0.5f);
        total += (mult - 1.f) * bwv;
      }
    }
    atomicAdd(out, -total);
  }
}

extern "C" void kernel_launch(void* const* d_in, const int* in_sizes, int n_in,
                              void* d_out, int out_size, void* d_ws, size_t ws_size,
                              hipStream_t stream) {
  const float* x       = (const float*)d_in[0];
  const float* y       = (const float*)d_in[1];
  const int*   compost = (const int*)d_in[2];
  const int*   recycle = (const int*)d_in[3];
  const int*   donate  = (const int*)d_in[4];
  const int*   wl_map  = (const int*)d_in[5];
  float* out = (float*)d_out;

  const int C  = in_sizes[5];
  const int B  = in_sizes[0] / C;
  const int n1 = in_sizes[2], n2 = in_sizes[3], n3 = in_sizes[4];

  hipMemsetAsync(out, 0, sizeof(float), stream);

  const size_t cntBytes = (size_t)B * 4;
  const size_t candOff  = (cntBytes + 15) & ~(size_t)15;
  const size_t need     = candOff + (size_t)B * SLOTS * 8;

  if (d_ws != nullptr && ws_size >= need) {
    unsigned* cnt = (unsigned*)d_ws;
    unsigned long long* cand = (unsigned long long*)((char*)d_ws + candOff);
    hipMemsetAsync(cnt, 0, cntBytes, stream);

    const size_t totalS = (size_t)B * (size_t)C;
    const unsigned total = (unsigned)totalS;
    size_t n4s = totalS / 4;
    int nblk = (int)((n4s + 255) / 256);
    if (nblk > 2048) nblk = 2048;   // 2048 x 256 = exact resident capacity
    if (nblk < 1) nblk = 1;

    stream_kernel<<<nblk, 256, 0, stream>>>(x, y, out, cnt, cand, C, total);
    topk_kernel<<<B, 64, 0, stream>>>(x, y, compost, recycle, donate, wl_map,
                                      out, cnt, cand, C, n1, n2, n3);
  } else {
    asl_kernel<<<B, 256, 0, stream>>>(x, y, compost, recycle, donate, wl_map,
                                      out, C, n1, n2, n3);
  }
}

// Round 4
// 206.810 us; speedup vs baseline: 1.1969x; 1.1938x over previous
//
#include <hip/hip_runtime.h>

#define TOPK 10
#define CLIP 0.05f
#define EPSV 1e-8f
#define ALPHA1 2.0f
#define ALPHA_OTHER 0.5f
#define TCAND 2.5f     // candidate threshold; guarded by exact fallback
#define MAXC 512
#define LN2F 0.69314718056f

// sortable packed key: (monotone float key << 32) | (C - col)
// larger packed = larger value; on equal value, smaller col wins (matches lax.top_k)
// NOTE: built from raw x bits -> top-k ordering is immune to sigmoid numerics.
__device__ __forceinline__ unsigned long long pack_vc(float v, int c, int C) {
  unsigned u = __float_as_uint(v);
  unsigned key = (u & 0x80000000u) ? ~u : (u | 0x80000000u);
  return ((unsigned long long)key << 32) | (unsigned)(C - c);
}
__device__ __forceinline__ float unpack_v(unsigned long long p) {
  unsigned key = (unsigned)(p >> 32);
  unsigned u = (key & 0x80000000u) ? (key & 0x7fffffffu) : ~key;
  return __uint_as_float(u);
}
__device__ __forceinline__ int unpack_c(unsigned long long p, int C) {
  return C - (int)(unsigned)(p & 0xffffffffu);
}

// (base * w) in LOG2 UNITS for one element; caller scales the final sum by ln2.
// pos = (y == 1). Fast path: v_rcp instead of IEEE div (~1 ulp), native v_log2.
// ~15 VALU instrs/element vs ~26-30 for the exact-div version.
__device__ __forceinline__ float base_w(float xv, bool pos) {
  float u = __expf(-xv);                       // v_mul + v_exp
  float r = __builtin_amdgcn_rcpf(1.f + u);    // sigmoid, fast rcp (~1 ulp)
  float xneg = fminf(1.05f - r, 1.f);          // min(1 - p + clip, 1)
  float q = pos ? r : xneg;
  float b2 = __log2f(fmaxf(q, EPSV));          // log2(q): native v_log, no ln2 mul
  float t = 1.f - q;                           // 1 - pt
  float t2 = t * t;
  float w = pos ? t : t2 * t2;                 // gamma: pos=1, neg=4
  return b2 * w;                               // log2-units
}

// process one float4: accumulate into 4 independent chains, set candidate bit
__device__ __forceinline__ void proc4(float4 X, float4 Y, float4& acc,
                                      unsigned& cmask, int slot) {
  acc.x += base_w(X.x, Y.x > 0.5f);
  acc.y += base_w(X.y, Y.y > 0.5f);
  acc.z += base_w(X.z, Y.z > 0.5f);
  acc.w += base_w(X.w, Y.w > 0.5f);
  float mx = fmaxf(fmaxf(X.x, X.y), fmaxf(X.z, X.w));
  cmask |= (mx > TCAND ? 1u : 0u) << slot;
}

__global__ __launch_bounds__(256) void asl_kernel(
    const float* __restrict__ x, const float* __restrict__ y,
    const int* __restrict__ compost, const int* __restrict__ recycle,
    const int* __restrict__ donate, const int* __restrict__ wl_map,
    float* __restrict__ out, int C, int n1, int n2, int n3)
{
  const int row = blockIdx.x;
  const float* xr = x + (size_t)row * (size_t)C;
  const float* yr = y + (size_t)row * (size_t)C;
  const int tid = threadIdx.x;
  const int lane = tid & 63;
  const int wave = tid >> 6;

  __shared__ int s_has[3];
  __shared__ unsigned s_cnt;
  __shared__ unsigned long long s_cand[MAXC];
  __shared__ float s_sum[4];
  __shared__ unsigned long long s_top[TOPK];

  if (tid < 3) s_has[tid] = 0;
  if (tid == 0) s_cnt = 0;
  __syncthreads();

  // early-issue whitelist gather: load now, test AFTER the stream loop so the
  // scattered-load latency hides under the streaming work
  const int ntot = n1 + n2 + n3;
  float gflag = 0.f; int gwhich = -1;
  if (tid < ntot) {
    int colI;
    if (tid < n1)           { gwhich = 0; colI = compost[tid]; }
    else if (tid < n1 + n2) { gwhich = 1; colI = recycle[tid - n1]; }
    else                    { gwhich = 2; colI = donate[tid - n1 - n2]; }
    gflag = yr[colI];
  }

  float ssc = 0.f;  // scalar-edge contributions (log2 units)

#define PUSH(V, CCOL)                                                     \
  do {                                                                    \
    unsigned _i = atomicAdd(&s_cnt, 1u);                                  \
    if (_i < MAXC) s_cand[_i] = pack_vc((V), (CCOL), C);                  \
  } while (0)
#define PROC_DIRECT(XV, YV, COL)                                          \
  do {                                                                    \
    float _xv = (XV);                                                     \
    ssc += base_w(_xv, (YV) > 0.5f);                                      \
    if (_xv > TCAND) PUSH(_xv, (COL));                                    \
  } while (0)

  // alignment prologue: make float4 base 16B-aligned (row*C mod 4 varies)
  int lead = (int)((4u - ((unsigned)((size_t)row * (size_t)C) & 3u)) & 3u);
  if (lead > C) lead = C;
  for (int col = tid; col < lead; col += 256) PROC_DIRECT(xr[col], yr[col], col);

  const int nvec = (C - lead) >> 2;
  const float4* __restrict__ x4 = (const float4*)(xr + lead);
  const float4* __restrict__ y4 = (const float4*)(yr + lead);

  float4 sacc = make_float4(0.f, 0.f, 0.f, 0.f);
  unsigned cmask = 0;

  // main loop: 4x unrolled, 8 loads batch-issued, candidates deferred to a bitmask
  int slotbase = 0;
  for (int base = tid; base < nvec; base += 1024, slotbase += 4) {
    const bool v1 = base + 256 < nvec;
    const bool v2 = base + 512 < nvec;
    const bool v3 = base + 768 < nvec;
    float4 xv0, xv1, xv2, xv3, yv0, yv1, yv2, yv3;
    xv0 = x4[base];                 yv0 = y4[base];
    if (v1) { xv1 = x4[base + 256]; yv1 = y4[base + 256]; }
    if (v2) { xv2 = x4[base + 512]; yv2 = y4[base + 512]; }
    if (v3) { xv3 = x4[base + 768]; yv3 = y4[base + 768]; }
    proc4(xv0, yv0, sacc, cmask, slotbase + 0);
    if (v1) proc4(xv1, yv1, sacc, cmask, slotbase + 1);
    if (v2) proc4(xv2, yv2, sacc, cmask, slotbase + 2);
    if (v3) proc4(xv3, yv3, sacc, cmask, slotbase + 3);
  }

  // scalar tail
  for (int col = lead + nvec * 4 + tid; col < C; col += 256)
    PROC_DIRECT(xr[col], yr[col], col);

  // flush whitelist flags (benign write-1 races)
  if (gwhich >= 0 && gflag > 0.5f) s_has[gwhich] = 1;
  for (int i = 256 + tid; i < ntot; i += 256) {  // generic remainder (empty here)
    int which, colI;
    if (i < n1)           { which = 0; colI = compost[i]; }
    else if (i < n1 + n2) { which = 1; colI = recycle[i - n1]; }
    else                  { which = 2; colI = donate[i - n1 - n2]; }
    if (yr[colI] > 0.5f) s_has[which] = 1;
  }

  // materialize candidates from the bitmask (cache-warm reloads, off hot path)
  while (cmask) {
    int b = __ffs(cmask) - 1;
    cmask &= cmask - 1;
    int o = b >> 2, j = b & 3;
    int i = tid + o * 1024 + j * 256;
    float4 X = x4[i];
    int cb = lead + i * 4;
    if (X.x > TCAND) PUSH(X.x, cb + 0);
    if (X.y > TCAND) PUSH(X.y, cb + 1);
    if (X.z > TCAND) PUSH(X.z, cb + 2);
    if (X.w > TCAND) PUSH(X.w, cb + 3);
  }
#undef PROC_DIRECT
#undef PUSH

  // wave reduce the sum (log2 units)
  float sum = ssc + sacc.x + sacc.y + sacc.z + sacc.w;
#pragma unroll
  for (int off = 32; off > 0; off >>= 1) sum += __shfl_xor(sum, off, 64);
  if (lane == 0) s_sum[wave] = sum;
  __syncthreads();

  // wave 0: exact top-10 selection
  if (wave == 0) {
    const unsigned cnt = s_cnt;
    unsigned long long ls[TOPK];   // per-lane sorted (desc) packed list; 0 = pad
#pragma unroll
    for (int s = 0; s < TOPK; s++) ls[s] = 0ULL;

#define INSERT(P)                                                          \
    do {                                                                   \
      unsigned long long _p = (P);                                         \
      if (_p > ls[TOPK - 1]) {                                             \
        _Pragma("unroll")                                                  \
        for (int _s = 0; _s < TOPK; _s++) {                                \
          bool _g = _p > ls[_s];                                           \
          unsigned long long _t = _g ? ls[_s] : _p;                        \
          ls[_s] = _g ? _p : ls[_s];                                       \
          _p = _t;                                                         \
        }                                                                  \
      }                                                                    \
    } while (0)

    if (cnt >= TOPK && cnt <= MAXC) {
      for (unsigned i = lane; i < cnt; i += 64) INSERT(s_cand[i]);
    } else {
      // exact fallback: rescan the (cache-resident) row
      for (int col = lane; col < C; col += 64) INSERT(pack_vc(xr[col], col, C));
    }
#undef INSERT

    // 10 rounds of 64-lane packed max; pop winner (packed values unique)
    for (int r = 0; r < TOPK; r++) {
      unsigned long long mine = ls[0];
      unsigned long long best = mine;
#pragma unroll
      for (int off = 32; off > 0; off >>= 1) {
        unsigned long long o = __shfl_xor(best, off, 64);
        best = (o > best) ? o : best;
      }
      if (lane == 0) s_top[r] = best;
      if (mine == best) {
#pragma unroll
        for (int s = 0; s < TOPK - 1; s++) ls[s] = ls[s + 1];
        ls[TOPK - 1] = 0ULL;
      }
    }
  }
  __syncthreads();

  if (tid == 0) {
    float total = s_sum[0] + s_sum[1] + s_sum[2] + s_sum[3];
    const bool h1 = s_has[0] != 0, h2 = s_has[1] != 0, h3 = s_has[2] != 0;
    const bool gt4 = !(h1 || h2 || h3);

    // rank-sequential multiplier logic (mirrors the lax.scan)
    bool found = false;
    float fr[TOPK];
#pragma unroll
    for (int r = 0; r < TOPK; r++) {
      int col = unpack_c(s_top[r], C);
      int wl = wl_map[col];
      bool in_map = wl > 0;
      bool in_gt = (wl == 1 && h1) || (wl == 2 && h2) ||
                   (wl == 3 && h3) || (wl == 4 && gt4);
      float f = 1.f;
      if (in_map && gt4) f *= ALPHA_OTHER;
      if (in_map && !in_gt && !found) f *= ALPHA1;
      fr[r] = f;
      found = found || (in_map && in_gt);
    }
    const float extra = found ? 1.f : ALPHA1;
#pragma unroll
    for (int r = 0; r < TOPK; r++) {
      float mult = fr[r] * extra;
      if (mult != 1.f) {
        int col = unpack_c(s_top[r], C);
        float xv = unpack_v(s_top[r]);
        float bwv = base_w(xv, yr[col] > 0.5f);   // log2 units, consistent
        total += (mult - 1.f) * bwv;
      }
    }
    atomicAdd(out, -total * LN2F);   // scale log2-units -> natural log once
  }
}

extern "C" void kernel_launch(void* const* d_in, const int* in_sizes, int n_in,
                              void* d_out, int out_size, void* d_ws, size_t ws_size,
                              hipStream_t stream) {
  const float* x       = (const float*)d_in[0];
  const float* y       = (const float*)d_in[1];
  const int*   compost = (const int*)d_in[2];
  const int*   recycle = (const int*)d_in[3];
  const int*   donate  = (const int*)d_in[4];
  const int*   wl_map  = (const int*)d_in[5];
  float* out = (float*)d_out;

  const int C  = in_sizes[5];
  const int B  = in_sizes[0] / C;
  const int n1 = in_sizes[2], n2 = in_sizes[3], n3 = in_sizes[4];

  hipMemsetAsync(out, 0, sizeof(float), stream);
  asl_kernel<<<B, 256, 0, stream>>>(x, y, compost, recycle, donate, wl_map,
                                    out, C, n1, n2, n3);
}